// Round 9
// baseline (399.833 us; speedup 1.0000x reference)
//
#include <hip/hip_runtime.h>
#include <hip/hip_bf16.h>
#include <stdint.h>

#define BATCH 8192
#define DIM   2048
#define NEXP  8
#define BM    256
#define BN    128
#define BK    32
#define NITER (DIM / BK)   // 64 K-tiles
#define MTILES 40          // max Σ ceil(c_e/256) = 32 + 7 guard
#define NBLK  (DIM / BN)   // 16
#define XHALF 4096         // x gather blocks: 8192 rows / 2 per block
#define WCVTB 4096         // W cvt blocks

typedef __bf16 bf16x8 __attribute__((ext_vector_type(8)));
typedef float  f32x4  __attribute__((ext_vector_type(4)));

// ---- workspace layout ----
// metadata ints 0..511 (ntiles@48 tileExp@64 tilePos0@160 tileVal@256)
// rowmap @ int 512 (8192 ints)
// xg (bf16, compacted, 8448 rows incl. 256-row read slack) @ byte 40960
// Wb (bf16) @ byte 37,789,696
#define XG_BYTE_OFF 40960ull
#define WB_BYTE_OFF 37789696ull
#define WS_NEED     104898560ull

#define AS1(p) ((const __attribute__((address_space(1))) void*)(p))
#define AS3(p) ((__attribute__((address_space(3))) void*)(p))

__device__ __forceinline__ unsigned f2bf2(float lo, float hi) {
    unsigned ul = __float_as_uint(lo), uh = __float_as_uint(hi);
    ul = (ul + 0x7FFFu + ((ul >> 16) & 1u)) >> 16;   // RNE
    uh = (uh + 0x7FFFu + ((uh >> 16) & 1u)) >> 16;
    return (uh << 16) | ul;
}

// single block: histogram -> per-expert wave-parallel scan -> 256-row tile
// table (contiguous segments, NO padding) -> rowmap. No atomics.
// Tail tiles intentionally over-read into the next segment / xg slack; those
// acc rows are >= valid and never stored.
__global__ __launch_bounds__(512)
void k_plan(const int* __restrict__ ids, int* __restrict__ ws,
            int* __restrict__ rowmap) {
    __shared__ int sc[512 * NEXP];
    __shared__ int seg[NEXP];
    __shared__ int tot[NEXP];
    int t = threadIdx.x;
    int myids[16];
    int base = t * 16;
#pragma unroll
    for (int e = 0; e < NEXP; e++) sc[t * NEXP + e] = 0;
#pragma unroll
    for (int i = 0; i < 16; i++) {
        myids[i] = ids[base + i];
        sc[t * NEXP + myids[i]]++;
    }
    __syncthreads();
    {
        int w = t >> 6, l = t & 63;
        int e = w;
        int vals[8], sum = 0;
#pragma unroll
        for (int j = 0; j < 8; j++) { vals[j] = sc[(l * 8 + j) * NEXP + e]; sum += vals[j]; }
        int inc = sum;
        for (int d = 1; d < 64; d <<= 1) {
            int v = __shfl_up(inc, d, 64);
            if (l >= d) inc += v;
        }
        int run = inc - sum;
#pragma unroll
        for (int j = 0; j < 8; j++) { int v = vals[j]; sc[(l * 8 + j) * NEXP + e] = run; run += v; }
        if (l == 63) tot[e] = run;
    }
    __syncthreads();
    if (t == 0) {
        int pos = 0, mt = 0;
        for (int e = 0; e < NEXP; e++) {
            int c = tot[e];
            seg[e] = pos;
            int ntl = (c + BM - 1) / BM;
            for (int tt = 0; tt < ntl; tt++) {
                ws[64  + mt] = e;
                ws[160 + mt] = pos + tt * BM;
                int v = c - tt * BM;
                ws[256 + mt] = v < BM ? v : BM;
                mt++;
            }
            pos += c;                      // contiguous, no padding
        }
        ws[48] = mt;
    }
    __syncthreads();
#pragma unroll
    for (int i = 0; i < 16; i++) {
        int e = myids[i];
        int p = seg[e] + sc[t * NEXP + e]++;
        rowmap[p] = base + i;              // every p in [0,8192) written once
    }
}

// streaming prep (MLP-batched, r7-proven structure; no padding rows):
//   blocks [0, XHALF)       : 2 compacted rows each: xg[row]=bf16(x[rowmap[row]])
//   blocks [XHALF, +WCVTB)  : W fp32 -> bf16, 4 chunks/thread, load-batched
__global__ __launch_bounds__(256)
void k_prep(const float* __restrict__ x, const int* __restrict__ rowmap,
            unsigned short* __restrict__ xg,
            const float4* __restrict__ W, uint4* __restrict__ Wb) {
    int b = blockIdx.x;
    int t = threadIdx.x;
    if (b < XHALF) {
        int r0 = b * 2, r1 = r0 + 1;
        int m0 = rowmap[r0], m1 = rowmap[r1];
        const float4* s0 = (const float4*)(x + (size_t)m0 * DIM);
        const float4* s1 = (const float4*)(x + (size_t)m1 * DIM);
        float4 L0 = s0[2 * t], L1 = s0[2 * t + 1];
        float4 L2 = s1[2 * t], L3 = s1[2 * t + 1];
        uint4 v0, v1;
        v0.x = f2bf2(L0.x, L0.y); v0.y = f2bf2(L0.z, L0.w);
        v0.z = f2bf2(L1.x, L1.y); v0.w = f2bf2(L1.z, L1.w);
        v1.x = f2bf2(L2.x, L2.y); v1.y = f2bf2(L2.z, L2.w);
        v1.z = f2bf2(L3.x, L3.y); v1.w = f2bf2(L3.z, L3.w);
        ((uint4*)(xg + (size_t)r0 * DIM))[t] = v0;
        ((uint4*)(xg + (size_t)r1 * DIM))[t] = v1;
        return;
    }
    size_t base = (size_t)(b - XHALF) * 1024;
    float4 L[8];
#pragma unroll
    for (int k = 0; k < 4; k++) {
        size_t o = base + (size_t)k * 256 + t;
        L[2 * k]     = W[o * 2];
        L[2 * k + 1] = W[o * 2 + 1];
    }
#pragma unroll
    for (int k = 0; k < 4; k++) {
        size_t o = base + (size_t)k * 256 + t;
        uint4 v;
        v.x = f2bf2(L[2 * k].x,     L[2 * k].y);
        v.y = f2bf2(L[2 * k].z,     L[2 * k].w);
        v.z = f2bf2(L[2 * k + 1].x, L[2 * k + 1].y);
        v.w = f2bf2(L[2 * k + 1].z, L[2 * k + 1].w);
        Wb[o] = v;
    }
}

// grouped GEMM, deep-pipeline counted-vmcnt schedule:
// 256x128 tile, 8 waves (4M x 2N, per-wave 64x64), BK=32.
// LDS: ring of SIX K-tile buffers (A 16KB + B 8KB = 24KB each; 144 KB),
// prefetch distance 5. Per K-tile per thread: 3 global_load_lds (A:2, B:1).
// One iter = { vmcnt(12) [drains tile kt; tiles kt+1..kt+4 = 12 loads stay
// in flight] -> s_barrier -> 8 ds_read_b128 (buf kt%6) -> issue stage(kt+5)
// -> lgkmcnt(0) -> setprio(1) 16 MFMA setprio(0) }.  ONE barrier per iter.
// Tail peels 5 iters with vmcnt 12/9/6/3/0.
// Safety: vmcnt precedes the barrier (each wave's own 3 oldest = its share of
// stage(kt)) so after the barrier ALL waves' stage(kt) loads have landed;
// stage(kt+5) targets buf (kt-1)%6 whose ds_reads all completed before
// barrier(kt) (lgkm(0) before each wave's MFMA(kt-1)).  sched_barrier(0)
// after the barrier and after lgkmcnt pins the ordering (rule #18).
// Swizzle (proven r0/r7, 0-conflict): 16B granule at pos p of row r holds
// logical chunk p ^ ((r>>1)&3), applied on the staging SOURCE address.
// Grid dim3(16, MTILES): XCD = nb%8 (proven B-panel-per-XCD mapping).
__global__ __launch_bounds__(512)
void k_gemm(const unsigned short* __restrict__ xg,
            const unsigned short* __restrict__ Wb,
            const float* __restrict__ bias,
            const int* __restrict__ ws, const int* __restrict__ rowmap,
            float* __restrict__ out) {
    int mt = blockIdx.y;
    if (mt >= ws[48]) return;
    int e     = ws[64  + mt];
    int pos0  = ws[160 + mt];
    int valid = ws[256 + mt];
    int n0 = blockIdx.x * BN;

    __shared__ __align__(16) unsigned char lds[6 * 24576];  // 144 KB

    int tid = threadIdx.x;
    int w = tid >> 6, l = tid & 63;
    int l15 = l & 15, quad = l >> 4;
    int wm = (w >> 1) * 64, wn = (w & 1) * 64;

    const unsigned short* Abase = xg + (size_t)pos0 * DIM;
    const unsigned short* Bbase = Wb + ((size_t)e * DIM + n0) * DIM;

    // staging source offsets (shorts). A: 1024 granules (256 rows x 4),
    // wave w covers [w*128,+128) in 2 instrs. B: 512 granules (128 rows x 4),
    // wave w covers [w*64,+64) in 1 instr. granule g: row=g>>2, pos=g&3,
    // src chunk q = pos ^ ((row>>1)&3).
    int srcA[2], srcB0;
#pragma unroll
    for (int j = 0; j < 2; j++) {
        int g = w * 128 + j * 64 + l;
        int row = g >> 2, pos = g & 3;
        srcA[j] = row * DIM + (pos ^ ((row >> 1) & 3)) * 8;
    }
    {
        int h = w * 64 + l;
        int row = h >> 2, pos = h & 3;
        srcB0 = row * DIM + (pos ^ ((row >> 1) & 3)) * 8;
    }
    int dA0 = w * 2048;            // byte offsets within a buffer
    int dB0 = 16384 + w * 1024;

    // fragment read offsets (bytes within buffer), phys chunk = quad^((r>>1)&3)
    int swz = (quad ^ ((l15 >> 1) & 3)) * 16;
    int aOff[4], bOff[4];
#pragma unroll
    for (int i = 0; i < 4; i++) {
        aOff[i] = (wm + i * 16 + l15) * 64 + swz;
        bOff[i] = 16384 + (wn + i * 16 + l15) * 64 + swz;
    }

    f32x4 acc[4][4];
#pragma unroll
    for (int i = 0; i < 4; i++)
#pragma unroll
        for (int j = 0; j < 4; j++) acc[i][j] = (f32x4){0.f, 0.f, 0.f, 0.f};

#define GL(srcp, dstoff)                                                        \
    __builtin_amdgcn_global_load_lds(AS1(srcp), AS3(lds + (dstoff)), 16, 0, 0)
#define STAGE(bb, k0)                                                           \
    do {                                                                        \
        GL(Abase + (k0) + srcA[0], (bb) + dA0);                                 \
        GL(Abase + (k0) + srcA[1], (bb) + dA0 + 1024);                          \
        GL(Bbase + (k0) + srcB0,  (bb) + dB0);                                  \
    } while (0)
#define VMCNT(NSTR) asm volatile("s_waitcnt vmcnt(" NSTR ")" ::: "memory")

#define BODY(ktv, curb, DOPRE, preb, NSTR)                                      \
    do {                                                                        \
        VMCNT(NSTR);                                                            \
        __builtin_amdgcn_s_barrier();                                           \
        __builtin_amdgcn_sched_barrier(0);                                      \
        const unsigned char* pb = lds + (curb);                                 \
        bf16x8 af[4], bf[4];                                                    \
        _Pragma("unroll")                                                       \
        for (int i_ = 0; i_ < 4; i_++) af[i_] = *(const bf16x8*)(pb + aOff[i_]);\
        _Pragma("unroll")                                                       \
        for (int i_ = 0; i_ < 4; i_++) bf[i_] = *(const bf16x8*)(pb + bOff[i_]);\
        if (DOPRE) STAGE(preb, ((ktv) + 5) * BK);                               \
        asm volatile("s_waitcnt lgkmcnt(0)" ::: "memory");                      \
        __builtin_amdgcn_sched_barrier(0);                                      \
        __builtin_amdgcn_s_setprio(1);                                          \
        _Pragma("unroll")                                                       \
        for (int mi_ = 0; mi_ < 4; mi_++)                                       \
            _Pragma("unroll")                                                   \
            for (int ni_ = 0; ni_ < 4; ni_++)                                   \
                acc[mi_][ni_] = __builtin_amdgcn_mfma_f32_16x16x32_bf16(        \
                    af[mi_], bf[ni_], acc[mi_][ni_], 0, 0, 0);                  \
        __builtin_amdgcn_s_setprio(0);                                          \
    } while (0)

    // prologue: stage K-tiles 0..4 into bufs 0..4 (15 loads/wave in flight)
#pragma unroll
    for (int t5 = 0; t5 < 5; ++t5) STAGE(t5 * 24576, t5 * BK);

    // main loop: kt = 0..NITER-6; steady outstanding before wait = 15
    {
        int cur = 0;                       // kt % 6
        for (int kt = 0; kt < NITER - 5; ++kt) {
            int pre = (cur == 0) ? 5 : cur - 1;   // (kt+5) % 6 == (kt-1) % 6
            BODY(kt, cur * 24576, true, pre * 24576, "12");
            cur = (cur == 5) ? 0 : cur + 1;
        }
    }
    // peeled tail: kt = NITER-5 .. NITER-1 (no more staging)
    BODY(NITER - 5, ((NITER - 5) % 6) * 24576, false, 0, "12");
    BODY(NITER - 4, ((NITER - 4) % 6) * 24576, false, 0, "9");
    BODY(NITER - 3, ((NITER - 3) % 6) * 24576, false, 0, "6");
    BODY(NITER - 2, ((NITER - 2) % 6) * 24576, false, 0, "3");
    BODY(NITER - 1, ((NITER - 1) % 6) * 24576, false, 0, "0");
#undef BODY
#undef VMCNT
#undef STAGE
#undef GL

    // epilogue: bias + relu + residual(from xg, bf16) + scatter
    float bv[4];
#pragma unroll
    for (int ni = 0; ni < 4; ni++)
        bv[ni] = bias[(size_t)e * DIM + n0 + wn + ni * 16 + l15];
#pragma unroll
    for (int mi = 0; mi < 4; mi++) {
#pragma unroll
        for (int r4 = 0; r4 < 4; r4++) {
            int rl = wm + mi * 16 + quad * 4 + r4;
            if (rl < valid) {
                int orig = rowmap[pos0 + rl];
                const unsigned short* xrow = xg + (size_t)(pos0 + rl) * DIM + n0;
                float* orow = out + (size_t)orig * DIM + n0;
#pragma unroll
                for (int ni = 0; ni < 4; ni++) {
                    int col = wn + ni * 16 + l15;
                    float xv = __uint_as_float((unsigned)xrow[col] << 16);
                    float v = acc[mi][ni][r4] + bv[ni];
                    v = v > 0.f ? v : 0.f;
                    orow[col] = xv + v;
                }
            }
        }
    }
}

// slow-but-correct fallback if workspace is too small
__global__ void k_naive(const float* __restrict__ x, const int* __restrict__ ids,
                        const float* __restrict__ W, const float* __restrict__ b,
                        float* __restrict__ out) {
    __shared__ float lx[DIM];
    int i = blockIdx.x;
    for (int t = threadIdx.x; t < DIM; t += blockDim.x) lx[t] = x[(size_t)i * DIM + t];
    __syncthreads();
    int e = ids[i];
    const float* We = W + (size_t)e * DIM * DIM;
    for (int n = threadIdx.x; n < DIM; n += blockDim.x) {
        const float* wr = We + (size_t)n * DIM;
        float acc = 0.f;
        for (int k = 0; k < DIM; k += 4) {
            float4 w4 = *(const float4*)(wr + k);
            acc += lx[k] * w4.x + lx[k + 1] * w4.y + lx[k + 2] * w4.z + lx[k + 3] * w4.w;
        }
        float v = acc + b[(size_t)e * DIM + n];
        v = v > 0.f ? v : 0.f;
        out[(size_t)i * DIM + n] = lx[n] + v;
    }
}

extern "C" void kernel_launch(void* const* d_in, const int* in_sizes, int n_in,
                              void* d_out, int out_size, void* d_ws, size_t ws_size,
                              hipStream_t stream) {
    const float* x   = (const float*)d_in[0];
    const int*   ids = (const int*)d_in[1];
    const float* W   = (const float*)d_in[2];
    const float* b   = (const float*)d_in[3];
    float* out = (float*)d_out;

    if (ws_size < WS_NEED) {
        k_naive<<<BATCH, 256, 0, stream>>>(x, ids, W, b, out);
        return;
    }

    char* wsb = (char*)d_ws;
    int*  wsi = (int*)wsb;
    int* rowmap = wsi + 512;
    unsigned short* xg = (unsigned short*)(wsb + XG_BYTE_OFF);
    unsigned short* Wb = (unsigned short*)(wsb + WB_BYTE_OFF);

    k_plan<<<1, 512, 0, stream>>>(ids, wsi, rowmap);
    k_prep<<<XHALF + WCVTB, 256, 0, stream>>>(x, rowmap, xg,
                                              (const float4*)W, (uint4*)Wb);
    dim3 g(NBLK, MTILES);
    k_gemm<<<g, 512, 0, stream>>>(xg, Wb, b, wsi, rowmap, out);
}